// Round 8
// baseline (211.738 us; speedup 1.0000x reference)
//
#include <hip/hip_runtime.h>
#include <hip/hip_bf16.h>

#define MODEL 1024
#define NHEADS 16
#define HDIM 64
#define BATCH 2
#define SEQ 2048
#define NROWS (BATCH*SEQ)   // 4096
#define QKVN (3*MODEL)      // 3072
#define QSCALE 0.1803368801111204f  // 0.125 * log2(e): folded into Q; softmax uses exp2

typedef __bf16 bf16x8 __attribute__((ext_vector_type(8)));
typedef float f32x4 __attribute__((ext_vector_type(4)));
typedef float f32x16 __attribute__((ext_vector_type(16)));

#define GLDS(g, l) __builtin_amdgcn_global_load_lds( \
    (const __attribute__((address_space(1))) void*)(g), \
    (__attribute__((address_space(3))) void*)(l), 16, 0, 0)

__device__ inline unsigned cvtpk(float lo, float hi) {  // lo -> bits[15:0], hi -> bits[31:16]
    unsigned r;
    asm("v_cvt_pk_bf16_f32 %0, %1, %2" : "=v"(r) : "v"(lo), "v"(hi));
    return r;
}

// fragment-major index split into additive s- and d-parts (qk: [t64][r2*4+st][lane][8])
__device__ inline int qk_fs(int s) { return ((s >> 6) << 12) + (((s >> 5) & 1) << 11) + ((s & 31) << 3); }
__device__ inline int qk_fd(int d) { return ((d >> 4) << 9) + (((d >> 3) & 1) << 8) + (d & 7); }
// v^T: [t64][dr2*4+ks][lane][8]
__device__ inline int v_fs(int s) { return ((s >> 6) << 12) + (((s >> 4) & 3) << 9) + (((s >> 3) & 1) << 8) + (s & 7); }
__device__ inline int v_fd(int d) { return ((d >> 5) << 11) + ((d & 31) << 3); }

// ---------------- fused prep: emb->bf16, w_qkv^T->bf16, w_out^T->bf16 ----------------
// blocks [0,4096): cvt; [4096,7168): tcvt w_qkv; [7168,8192): tcvt w_out

__global__ __launch_bounds__(256) void prep_kernel(
    const float* __restrict__ emb, __hip_bfloat16* __restrict__ Xb,
    const float* __restrict__ wqkv, __hip_bfloat16* __restrict__ Wqkvt,
    const float* __restrict__ wout, __hip_bfloat16* __restrict__ Woutt)
{
    __shared__ float tile[32][33];
    int bid = blockIdx.x, tid = threadIdx.x;
    if (bid < 4096) {
        int i = (bid * 256 + tid) * 4;
        float4 v = *(const float4*)(emb + i);
        Xb[i + 0] = __float2bfloat16(v.x);
        Xb[i + 1] = __float2bfloat16(v.y);
        Xb[i + 2] = __float2bfloat16(v.z);
        Xb[i + 3] = __float2bfloat16(v.w);
        return;
    }
    const float* in; __hip_bfloat16* out; int K, N, n0, k0;
    if (bid < 7168) {
        int t = bid - 4096; in = wqkv; out = Wqkvt; K = MODEL; N = QKVN;
        n0 = (t % 96) * 32; k0 = (t / 96) * 32;
    } else {
        int t = bid - 7168; in = wout; out = Woutt; K = MODEL; N = MODEL;
        n0 = (t & 31) * 32; k0 = (t >> 5) * 32;
    }
    int tx = tid & 31, ty = tid >> 5;
#pragma unroll
    for (int i = 0; i < 4; ++i)
        tile[ty + i * 8][tx] = in[(size_t)(k0 + ty + i * 8) * N + n0 + tx];
    __syncthreads();
#pragma unroll
    for (int i = 0; i < 4; ++i)
        out[(size_t)(n0 + ty + i * 8) * K + k0 + tx] = __float2bfloat16(tile[tx][ty + i * 8]);
}

// ---------------- GEMM: C[M,N] = A[M,K] @ Bt[N,K]^T + bias (BK=64, m97 structure) ----------------
// EPI 0: scatter q (scaled) / k / v into MFMA-fragment-major buffers; EPI 1: fp32 C + bias.

template<int EPI>
__global__ __launch_bounds__(256) void gemm_bt_kernel(
    const __hip_bfloat16* __restrict__ A, const __hip_bfloat16* __restrict__ Bt,
    const float* __restrict__ bias, float* __restrict__ Cf,
    __hip_bfloat16* __restrict__ qb, __hip_bfloat16* __restrict__ kb,
    __hip_bfloat16* __restrict__ vb, int M, int N, int K)
{
    __shared__ __hip_bfloat16 As[128 * 64];
    __shared__ __hip_bfloat16 Bs[128 * 64];
    int tid = threadIdx.x;
    int lane = tid & 63, wv = tid >> 6;
    int wm = wv >> 1, wn = wv & 1;
    int g = lane >> 4, li = lane & 15;
    int row0 = blockIdx.y * 128, col0 = blockIdx.x * 128;

    f32x4 acc[4][4] = {};

    for (int kt = 0; kt < K; kt += 64) {
        __syncthreads();
#pragma unroll
        for (int s4 = 0; s4 < 4; ++s4) {
            int idx = (s4 * 256 + tid) * 8;
            int r = idx >> 6, c = idx & 63;
            GLDS(A + (size_t)(row0 + r) * K + kt + c, (char*)As + (size_t)(s4 * 4 + wv) * 1024);
            GLDS(Bt + (size_t)(col0 + r) * K + kt + c, (char*)Bs + (size_t)(s4 * 4 + wv) * 1024);
        }
        __syncthreads();
        bf16x8 a[2][4], b[2][4];
#pragma unroll
        for (int kk = 0; kk < 2; ++kk) {
#pragma unroll
            for (int m = 0; m < 4; ++m)
                a[kk][m] = *(const bf16x8*)((const char*)As + (size_t)(((wm * 64 + m * 16 + li) * 64 + kk * 32 + g * 8) * 2));
#pragma unroll
            for (int n = 0; n < 4; ++n)
                b[kk][n] = *(const bf16x8*)((const char*)Bs + (size_t)(((wn * 64 + n * 16 + li) * 64 + kk * 32 + g * 8) * 2));
        }
#pragma unroll
        for (int m = 0; m < 4; ++m)
#pragma unroll
            for (int n = 0; n < 4; ++n) {
                acc[m][n] = __builtin_amdgcn_mfma_f32_16x16x32_bf16(a[0][m], b[0][n], acc[m][n], 0, 0, 0);
                acc[m][n] = __builtin_amdgcn_mfma_f32_16x16x32_bf16(a[1][m], b[1][n], acc[m][n], 0, 0, 0);
            }
    }

    if (EPI == 1) {
#pragma unroll
        for (int m = 0; m < 4; ++m) {
            int row = row0 + wm * 64 + m * 16 + g * 4;
#pragma unroll
            for (int n = 0; n < 4; ++n) {
                int col = col0 + wn * 64 + n * 16 + li;
                float bv = bias[col];
#pragma unroll
                for (int r = 0; r < 4; ++r)
                    Cf[(size_t)(row + r) * N + col] = acc[m][n][r] + bv;
            }
        }
    } else {
        // hoisted per-n scatter info
        __hip_bfloat16* dstn[4];
        float bvn[4], qmn[4];
        int tpn[4];
#pragma unroll
        for (int n = 0; n < 4; ++n) {
            int col = col0 + wn * 64 + n * 16 + li;
            int h = col / 192;
            int rem = col - h * 192;
            int t = rem >> 6, d = rem & 63;
            tpn[n] = t;
            qmn[n] = (t == 0) ? QSCALE : 1.0f;
            bvn[n] = bias[col];
            __hip_bfloat16* base = (t == 0) ? qb : ((t == 1) ? kb : vb);
            dstn[n] = base + (size_t)h * (SEQ * HDIM) + ((t == 2) ? v_fd(d) : qk_fd(d));
        }
#pragma unroll
        for (int m = 0; m < 4; ++m)
#pragma unroll
            for (int r = 0; r < 4; ++r) {
                int row = row0 + wm * 64 + m * 16 + g * 4 + r;
                int s = row & 2047;
                int bofs = (row >> 11) * (NHEADS * SEQ * HDIM);
                int fsqk = qk_fs(s), fsv = v_fs(s);
#pragma unroll
                for (int n = 0; n < 4; ++n) {
                    float val = (acc[m][n][r] + bvn[n]) * qmn[n];
                    int off = bofs + ((tpn[n] == 2) ? fsv : fsqk);
                    dstn[n][off] = __float2bfloat16(val);
                }
            }
    }
}

// ---------------- flash attention (swapped-QK^T, split-KV, KVBLK=32) — Round-5 proven ----------------
// grid: (B*H=32, SEQ/64=32) = 1024 blocks. 256 threads = 4 waves: (qg = w&1) x (kvh = w>>1).
// Only change vs R5: l's cross-half shfl deferred to one post-loop shfl (m/al are hi-pair-symmetric).

__global__ __launch_bounds__(256, 4) void attn_kernel(
    const __hip_bfloat16* __restrict__ qfb, const __hip_bfloat16* __restrict__ kfb,
    const __hip_bfloat16* __restrict__ vfb, __hip_bfloat16* __restrict__ ctx)
{
    __shared__ float Ms[2][64], Ls[2][64], Os[2][32][64];
    int tid = threadIdx.x;
    int lane = tid & 63, w = tid >> 6;
    int qg = w & 1, kvh = w >> 1;
    int qi = lane & 31, hi = lane >> 5;
    int bh = blockIdx.x;
    int b = bh >> 4, h = bh & 15;
    int q0 = blockIdx.y * 64 + qg * 32;

    const bf16x8* QF = (const bf16x8*)qfb + (size_t)bh * 16384;  // 32 tiles * 512 frags-of-8
    const bf16x8* KF = (const bf16x8*)kfb + (size_t)bh * 16384;
    const bf16x8* VF = (const bf16x8*)vfb + (size_t)bh * 16384;

    bf16x8 qv[4];
#pragma unroll
    for (int st = 0; st < 4; ++st)
        qv[st] = QF[(size_t)blockIdx.y * 512 + (qg * 4 + st) * 64 + lane];

    f32x16 o0 = {}, o1 = {};
    float m = -INFINITY, l = 0.f;

    // preload K fragments for first tile of this wave's half
    bf16x8 kc[4], kn[4];
    {
        int t32 = kvh * 32, t64 = t32 >> 1, rh = t32 & 1;
#pragma unroll
        for (int st = 0; st < 4; ++st)
            kc[st] = KF[(size_t)t64 * 512 + (rh * 4 + st) * 64 + lane];
    }

    for (int tt = 0; tt < 32; ++tt) {
        int t32 = kvh * 32 + tt;
        int t64 = t32 >> 1, rh = t32 & 1;
        __builtin_amdgcn_s_barrier();  // align waves for cache reuse across qg pair

        // QK^T: S^T[k][q], one q-row per lane (Q pre-scaled by 0.125*log2e)
        f32x16 s = {};
#pragma unroll
        for (int st = 0; st < 4; ++st)
            s = __builtin_amdgcn_mfma_f32_32x32x16_bf16(kc[st], qv[st], s, 0, 0, 0);

        // issue V loads (this tile) + K loads (next tile); softmax hides latency
        bf16x8 vv[4];
#pragma unroll
        for (int dr = 0; dr < 2; ++dr)
#pragma unroll
            for (int ksl = 0; ksl < 2; ++ksl)
                vv[dr * 2 + ksl] = VF[(size_t)t64 * 512 + (dr * 4 + rh * 2 + ksl) * 64 + lane];
        {
            int tp = (tt < 31) ? t32 + 1 : t32;
            int p64 = tp >> 1, ph = tp & 1;
#pragma unroll
            for (int st = 0; st < 4; ++st)
                kn[st] = KF[(size_t)p64 * 512 + (ph * 4 + st) * 64 + lane];
        }

        // online softmax (log2 domain), tree max, defer-max rescale (THR=8)
        float tm[8];
#pragma unroll
        for (int i = 0; i < 8; ++i) tm[i] = fmaxf(s[i], s[8 + i]);
#pragma unroll
        for (int i = 0; i < 4; ++i) tm[i] = fmaxf(tm[i], tm[4 + i]);
        float mx = fmaxf(fmaxf(tm[0], tm[1]), fmaxf(tm[2], tm[3]));
        mx = fmaxf(mx, __shfl_xor(mx, 32));
        if (__any(mx - m > 8.0f)) {
            float mn = fmaxf(m, mx);
            float al = __builtin_amdgcn_exp2f(m - mn);
            m = mn;
            l *= al;
#pragma unroll
            for (int i = 0; i < 16; ++i) { o0[i] *= al; o1[i] *= al; }
        }
#pragma unroll
        for (int i = 0; i < 16; ++i) s[i] = __builtin_amdgcn_exp2f(s[i] - m);
        float ts[8];
#pragma unroll
        for (int i = 0; i < 8; ++i) ts[i] = s[i] + s[8 + i];
#pragma unroll
        for (int i = 0; i < 4; ++i) ts[i] = ts[i] + ts[4 + i];
        float sum = (ts[0] + ts[1]) + (ts[2] + ts[3]);
        l += sum;  // own-half partial; cross-half shfl deferred (m symmetric across hi)

        // P^T -> B-fragments: 8 cvt_pk + 4 half-wave shuffles (pre-selected payload)
        bf16x8 pb[2];
#pragma unroll
        for (int ksl = 0; ksl < 2; ++ksl) {
            const int base = ksl * 8;
            unsigned t0 = cvtpk(s[base + 0], s[base + 1]);
            unsigned t1 = cvtpk(s[base + 2], s[base + 3]);
            unsigned u0 = cvtpk(s[base + 4], s[base + 5]);
            unsigned u1 = cvtpk(s[base + 6], s[base + 7]);
            unsigned ra = __shfl_xor(hi ? t0 : u0, 32);
            unsigned rb = __shfl_xor(hi ? t1 : u1, 32);
            union { unsigned u[4]; bf16x8 v; } pk;
            pk.u[0] = hi ? ra : t0;
            pk.u[1] = hi ? rb : t1;
            pk.u[2] = hi ? u0 : ra;
            pk.u[3] = hi ? u1 : rb;
            pb[ksl] = pk.v;
        }

        // O^T[d][q] += V^T[d][k] @ P^T[k][q]
        o0 = __builtin_amdgcn_mfma_f32_32x32x16_bf16(vv[0], pb[0], o0, 0, 0, 0);
        o0 = __builtin_amdgcn_mfma_f32_32x32x16_bf16(vv[1], pb[1], o0, 0, 0, 0);
        o1 = __builtin_amdgcn_mfma_f32_32x32x16_bf16(vv[2], pb[0], o1, 0, 0, 0);
        o1 = __builtin_amdgcn_mfma_f32_32x32x16_bf16(vv[3], pb[1], o1, 0, 0, 0);

#pragma unroll
        for (int st = 0; st < 4; ++st) kc[st] = kn[st];
    }

    l += __shfl_xor(l, 32);  // deferred cross-half reduce

    // merge the two KV halves through LDS
    __syncthreads();
    if (kvh == 1) {
        Ms[qg][lane] = m; Ls[qg][lane] = l;
#pragma unroll
        for (int i = 0; i < 16; ++i) { Os[qg][i][lane] = o0[i]; Os[qg][16 + i][lane] = o1[i]; }
    }
    __syncthreads();
    if (kvh == 0) {
        float m2 = Ms[qg][lane], l2 = Ls[qg][lane];
        float mn = fmaxf(m, m2);
        float a = __builtin_amdgcn_exp2f(m - mn);
        float b2 = __builtin_amdgcn_exp2f(m2 - mn);
        float linv = 1.f / (l * a + l2 * b2);
        // epilogue: lane holds O^T[d][q=qi]; d = dt*32 + 8*rg + 4*hi + (0..3)
        __hip_bfloat16* crow = ctx + ((size_t)(b * SEQ) + q0 + qi) * MODEL + h * HDIM;
#pragma unroll
        for (int rg = 0; rg < 4; ++rg) {
            float c0[4], c1[4];
#pragma unroll
            for (int e = 0; e < 4; ++e) {
                int i = rg * 4 + e;
                c0[e] = (o0[i] * a + Os[qg][i][lane] * b2) * linv;
                c1[e] = (o1[i] * a + Os[qg][16 + i][lane] * b2) * linv;
            }
            uint2 pk0, pk1;
            pk0.x = cvtpk(c0[0], c0[1]); pk0.y = cvtpk(c0[2], c0[3]);
            pk1.x = cvtpk(c1[0], c1[1]); pk1.y = cvtpk(c1[2], c1[3]);
            *(uint2*)(crow + rg * 8 + hi * 4) = pk0;
            *(uint2*)(crow + 32 + rg * 8 + hi * 4) = pk1;
        }
    }
}

// ---------------- launch ----------------

extern "C" void kernel_launch(void* const* d_in, const int* in_sizes, int n_in,
                              void* d_out, int out_size, void* d_ws, size_t ws_size,
                              hipStream_t stream) {
    const float* emb = (const float*)d_in[0];
    const float* w_qkv = (const float*)d_in[1];
    const float* b_qkv = (const float*)d_in[2];
    const float* w_out = (const float*)d_in[3];
    const float* b_out = (const float*)d_in[4];
    float* out = (float*)d_out;
    char* ws = (char*)d_ws;

    __hip_bfloat16* Xb    = (__hip_bfloat16*)(ws);                       //  8 MB
    __hip_bfloat16* Wqkvt = (__hip_bfloat16*)(ws + ((size_t)8  << 20));  //  6 MB
    __hip_bfloat16* Woutt = (__hip_bfloat16*)(ws + ((size_t)14 << 20));  //  2 MB
    __hip_bfloat16* qbuf  = (__hip_bfloat16*)(ws + ((size_t)16 << 20));  //  8 MB (frag-major)
    __hip_bfloat16* kbuf  = (__hip_bfloat16*)(ws + ((size_t)24 << 20));  //  8 MB (frag-major)
    __hip_bfloat16* vbuf  = (__hip_bfloat16*)(ws + ((size_t)32 << 20));  //  8 MB (frag-major V^T)
    __hip_bfloat16* ctx   = (__hip_bfloat16*)(ws + ((size_t)40 << 20));  //  8 MB

    prep_kernel<<<8192, 256, 0, stream>>>(emb, Xb, w_qkv, Wqkvt, w_out, Woutt);

    gemm_bt_kernel<0><<<dim3(QKVN / 128, NROWS / 128), 256, 0, stream>>>(
        Xb, Wqkvt, b_qkv, nullptr, qbuf, kbuf, vbuf, NROWS, QKVN, MODEL);

    attn_kernel<<<dim3(BATCH * NHEADS, SEQ / 64), 256, 0, stream>>>(qbuf, kbuf, vbuf, ctx);

    gemm_bt_kernel<1><<<dim3(MODEL / 128, NROWS / 128), 256, 0, stream>>>(
        ctx, Woutt, b_out, out, nullptr, nullptr, nullptr, NROWS, MODEL, MODEL);
}

// Round 9
// 202.968 us; speedup vs baseline: 1.0432x; 1.0432x over previous
//
#include <hip/hip_runtime.h>
#include <hip/hip_bf16.h>

#define MODEL 1024
#define NHEADS 16
#define HDIM 64
#define BATCH 2
#define SEQ 2048
#define NROWS (BATCH*SEQ)   // 4096
#define QKVN (3*MODEL)      // 3072
#define QSCALE 0.1803368801111204f  // 0.125 * log2(e): folded into Q; softmax uses exp2

typedef __bf16 bf16x8 __attribute__((ext_vector_type(8)));
typedef float f32x4 __attribute__((ext_vector_type(4)));
typedef float f32x16 __attribute__((ext_vector_type(16)));

#define GLDS(g, l) __builtin_amdgcn_global_load_lds( \
    (const __attribute__((address_space(1))) void*)(g), \
    (__attribute__((address_space(3))) void*)(l), 16, 0, 0)

__device__ inline unsigned cvtpk(float lo, float hi) {  // lo -> bits[15:0], hi -> bits[31:16]
    unsigned r;
    asm("v_cvt_pk_bf16_f32 %0, %1, %2" : "=v"(r) : "v"(lo), "v"(hi));
    return r;
}

// fragment-major index split into additive s- and d-parts (qk: [t64][r2*4+st][lane][8])
__device__ inline int qk_fs(int s) { return ((s >> 6) << 12) + (((s >> 5) & 1) << 11) + ((s & 31) << 3); }
__device__ inline int qk_fd(int d) { return ((d >> 4) << 9) + (((d >> 3) & 1) << 8) + (d & 7); }
// v^T: [t64][dr2*4+ks][lane][8]
__device__ inline int v_fs(int s) { return ((s >> 6) << 12) + (((s >> 4) & 3) << 9) + (((s >> 3) & 1) << 8) + (s & 7); }
__device__ inline int v_fd(int d) { return ((d >> 5) << 11) + ((d & 31) << 3); }

// ---------------- fused prep: emb->bf16, w_qkv^T->bf16, w_out^T->bf16 ----------------
// blocks [0,4096): cvt; [4096,7168): tcvt w_qkv; [7168,8192): tcvt w_out

__global__ __launch_bounds__(256) void prep_kernel(
    const float* __restrict__ emb, __hip_bfloat16* __restrict__ Xb,
    const float* __restrict__ wqkv, __hip_bfloat16* __restrict__ Wqkvt,
    const float* __restrict__ wout, __hip_bfloat16* __restrict__ Woutt)
{
    __shared__ float tile[32][33];
    int bid = blockIdx.x, tid = threadIdx.x;
    if (bid < 4096) {
        int i = (bid * 256 + tid) * 4;
        float4 v = *(const float4*)(emb + i);
        Xb[i + 0] = __float2bfloat16(v.x);
        Xb[i + 1] = __float2bfloat16(v.y);
        Xb[i + 2] = __float2bfloat16(v.z);
        Xb[i + 3] = __float2bfloat16(v.w);
        return;
    }
    const float* in; __hip_bfloat16* out; int K, N, n0, k0;
    if (bid < 7168) {
        int t = bid - 4096; in = wqkv; out = Wqkvt; K = MODEL; N = QKVN;
        n0 = (t % 96) * 32; k0 = (t / 96) * 32;
    } else {
        int t = bid - 7168; in = wout; out = Woutt; K = MODEL; N = MODEL;
        n0 = (t & 31) * 32; k0 = (t >> 5) * 32;
    }
    int tx = tid & 31, ty = tid >> 5;
#pragma unroll
    for (int i = 0; i < 4; ++i)
        tile[ty + i * 8][tx] = in[(size_t)(k0 + ty + i * 8) * N + n0 + tx];
    __syncthreads();
#pragma unroll
    for (int i = 0; i < 4; ++i)
        out[(size_t)(n0 + ty + i * 8) * K + k0 + tx] = __float2bfloat16(tile[tx][ty + i * 8]);
}

// ---------------- GEMM: C[M,N] = A[M,K] @ Bt[N,K]^T + bias (BK=64, st-swizzled LDS) ----------------
// LDS tile [128][64] bf16 (128B rows) XOR-swizzled: LDS slot s' of row r holds global
// 16B-slot s'^(r&7). Applied on BOTH sides (rule 21): pre-swizzled global source for
// global_load_lds (linear dest) + same XOR on ds_read offsets -> 2-way bank alias (free).
// EPI 0: scatter q (scaled) / k / v into MFMA-fragment-major buffers; EPI 1: fp32 C + bias.

template<int EPI>
__global__ __launch_bounds__(256) void gemm_bt_kernel(
    const __hip_bfloat16* __restrict__ A, const __hip_bfloat16* __restrict__ Bt,
    const float* __restrict__ bias, float* __restrict__ Cf,
    __hip_bfloat16* __restrict__ qb, __hip_bfloat16* __restrict__ kb,
    __hip_bfloat16* __restrict__ vb, int M, int N, int K)
{
    __shared__ __hip_bfloat16 As[128 * 64];
    __shared__ __hip_bfloat16 Bs[128 * 64];
    int tid = threadIdx.x;
    int lane = tid & 63, wv = tid >> 6;
    int wm = wv >> 1, wn = wv & 1;
    int g = lane >> 4, li = lane & 15;
    int row0 = blockIdx.y * 128, col0 = blockIdx.x * 128;

    // staging source swizzle: lane's slot s'=tid&7, row r=s4*32+(tid>>3); fetch global slot s'^(r&7)
    int cswz = ((tid & 7) ^ ((tid >> 3) & 7)) * 8;

    f32x4 acc[4][4] = {};

    for (int kt = 0; kt < K; kt += 64) {
        __syncthreads();
#pragma unroll
        for (int s4 = 0; s4 < 4; ++s4) {
            int r = s4 * 32 + (tid >> 3);
            GLDS(A + (size_t)(row0 + r) * K + kt + cswz, (char*)As + (size_t)(s4 * 4 + wv) * 1024);
            GLDS(Bt + (size_t)(col0 + r) * K + kt + cswz, (char*)Bs + (size_t)(s4 * 4 + wv) * 1024);
        }
        __syncthreads();
        bf16x8 a[2][4], b[2][4];
#pragma unroll
        for (int kk = 0; kk < 2; ++kk) {
#pragma unroll
            for (int m = 0; m < 4; ++m) {
                int row = wm * 64 + m * 16 + li;
                a[kk][m] = *(const bf16x8*)((const char*)As + row * 128 + (((kk * 4 + g) ^ (li & 7)) << 4));
            }
#pragma unroll
            for (int n = 0; n < 4; ++n) {
                int row = wn * 64 + n * 16 + li;
                b[kk][n] = *(const bf16x8*)((const char*)Bs + row * 128 + (((kk * 4 + g) ^ (li & 7)) << 4));
            }
        }
#pragma unroll
        for (int m = 0; m < 4; ++m)
#pragma unroll
            for (int n = 0; n < 4; ++n) {
                acc[m][n] = __builtin_amdgcn_mfma_f32_16x16x32_bf16(a[0][m], b[0][n], acc[m][n], 0, 0, 0);
                acc[m][n] = __builtin_amdgcn_mfma_f32_16x16x32_bf16(a[1][m], b[1][n], acc[m][n], 0, 0, 0);
            }
    }

    if (EPI == 1) {
#pragma unroll
        for (int m = 0; m < 4; ++m) {
            int row = row0 + wm * 64 + m * 16 + g * 4;
#pragma unroll
            for (int n = 0; n < 4; ++n) {
                int col = col0 + wn * 64 + n * 16 + li;
                float bv = bias[col];
#pragma unroll
                for (int r = 0; r < 4; ++r)
                    Cf[(size_t)(row + r) * N + col] = acc[m][n][r] + bv;
            }
        }
    } else {
        // hoisted per-n scatter info
        __hip_bfloat16* dstn[4];
        float bvn[4], qmn[4];
        int tpn[4];
#pragma unroll
        for (int n = 0; n < 4; ++n) {
            int col = col0 + wn * 64 + n * 16 + li;
            int h = col / 192;
            int rem = col - h * 192;
            int t = rem >> 6, d = rem & 63;
            tpn[n] = t;
            qmn[n] = (t == 0) ? QSCALE : 1.0f;
            bvn[n] = bias[col];
            __hip_bfloat16* base = (t == 0) ? qb : ((t == 1) ? kb : vb);
            dstn[n] = base + (size_t)h * (SEQ * HDIM) + ((t == 2) ? v_fd(d) : qk_fd(d));
        }
#pragma unroll
        for (int m = 0; m < 4; ++m)
#pragma unroll
            for (int r = 0; r < 4; ++r) {
                int row = row0 + wm * 64 + m * 16 + g * 4 + r;
                int s = row & 2047;
                int bofs = (row >> 11) * (NHEADS * SEQ * HDIM);
                int fsqk = qk_fs(s), fsv = v_fs(s);
#pragma unroll
                for (int n = 0; n < 4; ++n) {
                    float val = (acc[m][n][r] + bvn[n]) * qmn[n];
                    int off = bofs + ((tpn[n] == 2) ? fsv : fsqk);
                    dstn[n][off] = __float2bfloat16(val);
                }
            }
    }
}

// ---------------- flash attention (swapped-QK^T, split-KV, KVBLK=32) — R8-proven, unchanged ----------------

__global__ __launch_bounds__(256, 4) void attn_kernel(
    const __hip_bfloat16* __restrict__ qfb, const __hip_bfloat16* __restrict__ kfb,
    const __hip_bfloat16* __restrict__ vfb, __hip_bfloat16* __restrict__ ctx)
{
    __shared__ float Ms[2][64], Ls[2][64], Os[2][32][64];
    int tid = threadIdx.x;
    int lane = tid & 63, w = tid >> 6;
    int qg = w & 1, kvh = w >> 1;
    int qi = lane & 31, hi = lane >> 5;
    int bh = blockIdx.x;
    int b = bh >> 4, h = bh & 15;
    int q0 = blockIdx.y * 64 + qg * 32;

    const bf16x8* QF = (const bf16x8*)qfb + (size_t)bh * 16384;  // 32 tiles * 512 frags-of-8
    const bf16x8* KF = (const bf16x8*)kfb + (size_t)bh * 16384;
    const bf16x8* VF = (const bf16x8*)vfb + (size_t)bh * 16384;

    bf16x8 qv[4];
#pragma unroll
    for (int st = 0; st < 4; ++st)
        qv[st] = QF[(size_t)blockIdx.y * 512 + (qg * 4 + st) * 64 + lane];

    f32x16 o0 = {}, o1 = {};
    float m = -INFINITY, l = 0.f;

    // preload K fragments for first tile of this wave's half
    bf16x8 kc[4], kn[4];
    {
        int t32 = kvh * 32, t64 = t32 >> 1, rh = t32 & 1;
#pragma unroll
        for (int st = 0; st < 4; ++st)
            kc[st] = KF[(size_t)t64 * 512 + (rh * 4 + st) * 64 + lane];
    }

    for (int tt = 0; tt < 32; ++tt) {
        int t32 = kvh * 32 + tt;
        int t64 = t32 >> 1, rh = t32 & 1;
        __builtin_amdgcn_s_barrier();  // align waves for cache reuse across qg pair

        // QK^T: S^T[k][q], one q-row per lane (Q pre-scaled by 0.125*log2e)
        f32x16 s = {};
#pragma unroll
        for (int st = 0; st < 4; ++st)
            s = __builtin_amdgcn_mfma_f32_32x32x16_bf16(kc[st], qv[st], s, 0, 0, 0);

        // issue V loads (this tile) + K loads (next tile); softmax hides latency
        bf16x8 vv[4];
#pragma unroll
        for (int dr = 0; dr < 2; ++dr)
#pragma unroll
            for (int ksl = 0; ksl < 2; ++ksl)
                vv[dr * 2 + ksl] = VF[(size_t)t64 * 512 + (dr * 4 + rh * 2 + ksl) * 64 + lane];
        {
            int tp = (tt < 31) ? t32 + 1 : t32;
            int p64 = tp >> 1, ph = tp & 1;
#pragma unroll
            for (int st = 0; st < 4; ++st)
                kn[st] = KF[(size_t)p64 * 512 + (ph * 4 + st) * 64 + lane];
        }

        // online softmax (log2 domain), tree max, defer-max rescale (THR=8)
        float tm[8];
#pragma unroll
        for (int i = 0; i < 8; ++i) tm[i] = fmaxf(s[i], s[8 + i]);
#pragma unroll
        for (int i = 0; i < 4; ++i) tm[i] = fmaxf(tm[i], tm[4 + i]);
        float mx = fmaxf(fmaxf(tm[0], tm[1]), fmaxf(tm[2], tm[3]));
        mx = fmaxf(mx, __shfl_xor(mx, 32));
        if (__any(mx - m > 8.0f)) {
            float mn = fmaxf(m, mx);
            float al = __builtin_amdgcn_exp2f(m - mn);
            m = mn;
            l *= al;
#pragma unroll
            for (int i = 0; i < 16; ++i) { o0[i] *= al; o1[i] *= al; }
        }
#pragma unroll
        for (int i = 0; i < 16; ++i) s[i] = __builtin_amdgcn_exp2f(s[i] - m);
        float ts[8];
#pragma unroll
        for (int i = 0; i < 8; ++i) ts[i] = s[i] + s[8 + i];
#pragma unroll
        for (int i = 0; i < 4; ++i) ts[i] = ts[i] + ts[4 + i];
        float sum = (ts[0] + ts[1]) + (ts[2] + ts[3]);
        l += sum;  // own-half partial; cross-half shfl deferred (m symmetric across hi)

        // P^T -> B-fragments: 8 cvt_pk + 4 half-wave shuffles (pre-selected payload)
        bf16x8 pb[2];
#pragma unroll
        for (int ksl = 0; ksl < 2; ++ksl) {
            const int base = ksl * 8;
            unsigned t0 = cvtpk(s[base + 0], s[base + 1]);
            unsigned t1 = cvtpk(s[base + 2], s[base + 3]);
            unsigned u0 = cvtpk(s[base + 4], s[base + 5]);
            unsigned u1 = cvtpk(s[base + 6], s[base + 7]);
            unsigned ra = __shfl_xor(hi ? t0 : u0, 32);
            unsigned rb = __shfl_xor(hi ? t1 : u1, 32);
            union { unsigned u[4]; bf16x8 v; } pk;
            pk.u[0] = hi ? ra : t0;
            pk.u[1] = hi ? rb : t1;
            pk.u[2] = hi ? u0 : ra;
            pk.u[3] = hi ? u1 : rb;
            pb[ksl] = pk.v;
        }

        // O^T[d][q] += V^T[d][k] @ P^T[k][q]
        o0 = __builtin_amdgcn_mfma_f32_32x32x16_bf16(vv[0], pb[0], o0, 0, 0, 0);
        o0 = __builtin_amdgcn_mfma_f32_32x32x16_bf16(vv[1], pb[1], o0, 0, 0, 0);
        o1 = __builtin_amdgcn_mfma_f32_32x32x16_bf16(vv[2], pb[0], o1, 0, 0, 0);
        o1 = __builtin_amdgcn_mfma_f32_32x32x16_bf16(vv[3], pb[1], o1, 0, 0, 0);

#pragma unroll
        for (int st = 0; st < 4; ++st) kc[st] = kn[st];
    }

    l += __shfl_xor(l, 32);  // deferred cross-half reduce

    // merge the two KV halves through LDS
    __syncthreads();
    if (kvh == 1) {
        Ms[qg][lane] = m; Ls[qg][lane] = l;
#pragma unroll
        for (int i = 0; i < 16; ++i) { Os[qg][i][lane] = o0[i]; Os[qg][16 + i][lane] = o1[i]; }
    }
    __syncthreads();
    if (kvh == 0) {
        float m2 = Ms[qg][lane], l2 = Ls[qg][lane];
        float mn = fmaxf(m, m2);
        float a = __builtin_amdgcn_exp2f(m - mn);
        float b2 = __builtin_amdgcn_exp2f(m2 - mn);
        float linv = 1.f / (l * a + l2 * b2);
        // epilogue: lane holds O^T[d][q=qi]; d = dt*32 + 8*rg + 4*hi + (0..3)
        __hip_bfloat16* crow = ctx + ((size_t)(b * SEQ) + q0 + qi) * MODEL + h * HDIM;
#pragma unroll
        for (int rg = 0; rg < 4; ++rg) {
            float c0[4], c1[4];
#pragma unroll
            for (int e = 0; e < 4; ++e) {
                int i = rg * 4 + e;
                c0[e] = (o0[i] * a + Os[qg][i][lane] * b2) * linv;
                c1[e] = (o1[i] * a + Os[qg][16 + i][lane] * b2) * linv;
            }
            uint2 pk0, pk1;
            pk0.x = cvtpk(c0[0], c0[1]); pk0.y = cvtpk(c0[2], c0[3]);
            pk1.x = cvtpk(c1[0], c1[1]); pk1.y = cvtpk(c1[2], c1[3]);
            *(uint2*)(crow + rg * 8 + hi * 4) = pk0;
            *(uint2*)(crow + 32 + rg * 8 + hi * 4) = pk1;
        }
    }
}

// ---------------- launch ----------------

extern "C" void kernel_launch(void* const* d_in, const int* in_sizes, int n_in,
                              void* d_out, int out_size, void* d_ws, size_t ws_size,
                              hipStream_t stream) {
    const float* emb = (const float*)d_in[0];
    const float* w_qkv = (const float*)d_in[1];
    const float* b_qkv = (const float*)d_in[2];
    const float* w_out = (const float*)d_in[3];
    const float* b_out = (const float*)d_in[4];
    float* out = (float*)d_out;
    char* ws = (char*)d_ws;

    __hip_bfloat16* Xb    = (__hip_bfloat16*)(ws);                       //  8 MB
    __hip_bfloat16* Wqkvt = (__hip_bfloat16*)(ws + ((size_t)8  << 20));  //  6 MB
    __hip_bfloat16* Woutt = (__hip_bfloat16*)(ws + ((size_t)14 << 20));  //  2 MB
    __hip_bfloat16* qbuf  = (__hip_bfloat16*)(ws + ((size_t)16 << 20));  //  8 MB (frag-major)
    __hip_bfloat16* kbuf  = (__hip_bfloat16*)(ws + ((size_t)24 << 20));  //  8 MB (frag-major)
    __hip_bfloat16* vbuf  = (__hip_bfloat16*)(ws + ((size_t)32 << 20));  //  8 MB (frag-major V^T)
    __hip_bfloat16* ctx   = (__hip_bfloat16*)(ws + ((size_t)40 << 20));  //  8 MB

    prep_kernel<<<8192, 256, 0, stream>>>(emb, Xb, w_qkv, Wqkvt, w_out, Woutt);

    gemm_bt_kernel<0><<<dim3(QKVN / 128, NROWS / 128), 256, 0, stream>>>(
        Xb, Wqkvt, b_qkv, nullptr, qbuf, kbuf, vbuf, NROWS, QKVN, MODEL);

    attn_kernel<<<dim3(BATCH * NHEADS, SEQ / 64), 256, 0, stream>>>(qbuf, kbuf, vbuf, ctx);

    gemm_bt_kernel<1><<<dim3(MODEL / 128, NROWS / 128), 256, 0, stream>>>(
        ctx, Woutt, b_out, out, nullptr, nullptr, nullptr, NROWS, MODEL, MODEL);
}

// Round 10
// 198.630 us; speedup vs baseline: 1.0660x; 1.0218x over previous
//
#include <hip/hip_runtime.h>
#include <hip/hip_bf16.h>

#define MODEL 1024
#define NHEADS 16
#define HDIM 64
#define BATCH 2
#define SEQ 2048
#define NROWS (BATCH*SEQ)   // 4096
#define QKVN (3*MODEL)      // 3072
#define QSCALE 0.1803368801111204f  // 0.125 * log2(e): folded into Q; softmax uses exp2

typedef __bf16 bf16x8 __attribute__((ext_vector_type(8)));
typedef float f32x4 __attribute__((ext_vector_type(4)));
typedef float f32x16 __attribute__((ext_vector_type(16)));

#define GLDS(g, l) __builtin_amdgcn_global_load_lds( \
    (const __attribute__((address_space(1))) void*)(g), \
    (__attribute__((address_space(3))) void*)(l), 16, 0, 0)

__device__ inline unsigned cvtpk(float lo, float hi) {  // lo -> bits[15:0], hi -> bits[31:16]
    unsigned r;
    asm("v_cvt_pk_bf16_f32 %0, %1, %2" : "=v"(r) : "v"(lo), "v"(hi));
    return r;
}

__device__ inline float max3f(float a, float b, float c) {
    float r;
    asm("v_max3_f32 %0, %1, %2, %3" : "=v"(r) : "v"(a), "v"(b), "v"(c));
    return r;
}

// fragment-major index split into additive s- and d-parts (qk: [t64][r2*4+st][lane][8])
__device__ inline int qk_fs(int s) { return ((s >> 6) << 12) + (((s >> 5) & 1) << 11) + ((s & 31) << 3); }
__device__ inline int qk_fd(int d) { return ((d >> 4) << 9) + (((d >> 3) & 1) << 8) + (d & 7); }
// v^T: [t64][dr2*4+ks][lane][8]
__device__ inline int v_fs(int s) { return ((s >> 6) << 12) + (((s >> 4) & 3) << 9) + (((s >> 3) & 1) << 8) + (s & 7); }
__device__ inline int v_fd(int d) { return ((d >> 5) << 11) + ((d & 31) << 3); }

// ---------------- fused prep: emb->bf16, w_qkv^T->bf16, w_out^T->bf16 ----------------
// blocks [0,4096): cvt; [4096,7168): tcvt w_qkv; [7168,8192): tcvt w_out

__global__ __launch_bounds__(256) void prep_kernel(
    const float* __restrict__ emb, __hip_bfloat16* __restrict__ Xb,
    const float* __restrict__ wqkv, __hip_bfloat16* __restrict__ Wqkvt,
    const float* __restrict__ wout, __hip_bfloat16* __restrict__ Woutt)
{
    __shared__ float tile[32][33];
    int bid = blockIdx.x, tid = threadIdx.x;
    if (bid < 4096) {
        int i = (bid * 256 + tid) * 4;
        float4 v = *(const float4*)(emb + i);
        Xb[i + 0] = __float2bfloat16(v.x);
        Xb[i + 1] = __float2bfloat16(v.y);
        Xb[i + 2] = __float2bfloat16(v.z);
        Xb[i + 3] = __float2bfloat16(v.w);
        return;
    }
    const float* in; __hip_bfloat16* out; int K, N, n0, k0;
    if (bid < 7168) {
        int t = bid - 4096; in = wqkv; out = Wqkvt; K = MODEL; N = QKVN;
        n0 = (t % 96) * 32; k0 = (t / 96) * 32;
    } else {
        int t = bid - 7168; in = wout; out = Woutt; K = MODEL; N = MODEL;
        n0 = (t & 31) * 32; k0 = (t >> 5) * 32;
    }
    int tx = tid & 31, ty = tid >> 5;
#pragma unroll
    for (int i = 0; i < 4; ++i)
        tile[ty + i * 8][tx] = in[(size_t)(k0 + ty + i * 8) * N + n0 + tx];
    __syncthreads();
#pragma unroll
    for (int i = 0; i < 4; ++i)
        out[(size_t)(n0 + ty + i * 8) * K + k0 + tx] = __float2bfloat16(tile[tx][ty + i * 8]);
}

// ---------------- GEMM: C[M,N] = A[M,K] @ Bt[N,K]^T + bias (BK=64, st-swizzled LDS) ----------------
// LDS tile [128][64] bf16 XOR-swizzled both sides (rule 21). XCD-chunked blockIdx swizzle (T1).
// EPI 0: scatter q (scaled) / k / v into MFMA-fragment-major buffers; EPI 1: fp32 C + bias.

template<int EPI>
__global__ __launch_bounds__(256) void gemm_bt_kernel(
    const __hip_bfloat16* __restrict__ A, const __hip_bfloat16* __restrict__ Bt,
    const float* __restrict__ bias, float* __restrict__ Cf,
    __hip_bfloat16* __restrict__ qb, __hip_bfloat16* __restrict__ kb,
    __hip_bfloat16* __restrict__ vb, int M, int N, int K)
{
    __shared__ __hip_bfloat16 As[128 * 64];
    __shared__ __hip_bfloat16 Bs[128 * 64];
    int tid = threadIdx.x;
    int lane = tid & 63, wv = tid >> 6;
    int wm = wv >> 1, wn = wv & 1;
    int g = lane >> 4, li = lane & 15;

    // XCD-chunked swizzle (nwg % 8 == 0 for both gemms -> bijective)
    int nbx = gridDim.x;
    int flat = blockIdx.y * nbx + blockIdx.x;
    int chunk = (nbx * gridDim.y) >> 3;
    int swz = (flat & 7) * chunk + (flat >> 3);
    int row0 = (swz / nbx) * 128, col0 = (swz % nbx) * 128;

    // staging source swizzle: lane's slot s'=tid&7, row r=s4*32+(tid>>3); fetch global slot s'^(r&7)
    int cswz = ((tid & 7) ^ ((tid >> 3) & 7)) * 8;

    f32x4 acc[4][4] = {};

    for (int kt = 0; kt < K; kt += 64) {
        __syncthreads();
#pragma unroll
        for (int s4 = 0; s4 < 4; ++s4) {
            int r = s4 * 32 + (tid >> 3);
            GLDS(A + (size_t)(row0 + r) * K + kt + cswz, (char*)As + (size_t)(s4 * 4 + wv) * 1024);
            GLDS(Bt + (size_t)(col0 + r) * K + kt + cswz, (char*)Bs + (size_t)(s4 * 4 + wv) * 1024);
        }
        __syncthreads();
        bf16x8 a[2][4], b[2][4];
#pragma unroll
        for (int kk = 0; kk < 2; ++kk) {
#pragma unroll
            for (int m = 0; m < 4; ++m) {
                int row = wm * 64 + m * 16 + li;
                a[kk][m] = *(const bf16x8*)((const char*)As + row * 128 + (((kk * 4 + g) ^ (li & 7)) << 4));
            }
#pragma unroll
            for (int n = 0; n < 4; ++n) {
                int row = wn * 64 + n * 16 + li;
                b[kk][n] = *(const bf16x8*)((const char*)Bs + row * 128 + (((kk * 4 + g) ^ (li & 7)) << 4));
            }
        }
#pragma unroll
        for (int m = 0; m < 4; ++m)
#pragma unroll
            for (int n = 0; n < 4; ++n) {
                acc[m][n] = __builtin_amdgcn_mfma_f32_16x16x32_bf16(a[0][m], b[0][n], acc[m][n], 0, 0, 0);
                acc[m][n] = __builtin_amdgcn_mfma_f32_16x16x32_bf16(a[1][m], b[1][n], acc[m][n], 0, 0, 0);
            }
    }

    if (EPI == 1) {
#pragma unroll
        for (int m = 0; m < 4; ++m) {
            int row = row0 + wm * 64 + m * 16 + g * 4;
#pragma unroll
            for (int n = 0; n < 4; ++n) {
                int col = col0 + wn * 64 + n * 16 + li;
                float bv = bias[col];
#pragma unroll
                for (int r = 0; r < 4; ++r)
                    Cf[(size_t)(row + r) * N + col] = acc[m][n][r] + bv;
            }
        }
    } else {
        // hoisted per-n scatter info
        __hip_bfloat16* dstn[4];
        float bvn[4], qmn[4];
        int tpn[4];
#pragma unroll
        for (int n = 0; n < 4; ++n) {
            int col = col0 + wn * 64 + n * 16 + li;
            int h = col / 192;
            int rem = col - h * 192;
            int t = rem >> 6, d = rem & 63;
            tpn[n] = t;
            qmn[n] = (t == 0) ? QSCALE : 1.0f;
            bvn[n] = bias[col];
            __hip_bfloat16* base = (t == 0) ? qb : ((t == 1) ? kb : vb);
            dstn[n] = base + (size_t)h * (SEQ * HDIM) + ((t == 2) ? v_fd(d) : qk_fd(d));
        }
#pragma unroll
        for (int m = 0; m < 4; ++m)
#pragma unroll
            for (int r = 0; r < 4; ++r) {
                int row = row0 + wm * 64 + m * 16 + g * 4 + r;
                int s = row & 2047;
                int bofs = (row >> 11) * (NHEADS * SEQ * HDIM);
                int fsqk = qk_fs(s), fsv = v_fs(s);
#pragma unroll
                for (int n = 0; n < 4; ++n) {
                    float val = (acc[m][n][r] + bvn[n]) * qmn[n];
                    int off = bofs + ((tpn[n] == 2) ? fsv : fsqk);
                    dstn[n][off] = __float2bfloat16(val);
                }
            }
    }
}

// ---------------- flash attention (swapped-QK^T, split-KV, KVBLK=32) ----------------
// XCD-chunked decode: each XCD owns 4 heads -> its K/V (2 MB) fits the 4 MB private L2.
// Pack via v_permlane32_swap_b32 (T12): one instr yields both B-frag words, no selects.
// Max tree via v_max3_f32 (T17). In-loop barrier removed (scheduling heuristic only).

__global__ __launch_bounds__(256, 4) void attn_kernel(
    const __hip_bfloat16* __restrict__ qfb, const __hip_bfloat16* __restrict__ kfb,
    const __hip_bfloat16* __restrict__ vfb, __hip_bfloat16* __restrict__ ctx)
{
    __shared__ float Ms[2][64], Ls[2][64], Os[2][32][64];
    int tid = threadIdx.x;
    int lane = tid & 63, w = tid >> 6;
    int qg = w & 1, kvh = w >> 1;
    int qi = lane & 31, hi = lane >> 5;

    // XCD-chunked swizzle: bid%8 -> XCD; chunk of 128 consecutive swz = 4 heads
    int bid = blockIdx.y * 32 + blockIdx.x;
    int swz = (bid & 7) * 128 + (bid >> 3);
    int bh = swz >> 5, qt = swz & 31;
    int b = bh >> 4, h = bh & 15;
    int q0 = qt * 64 + qg * 32;

    const bf16x8* QF = (const bf16x8*)qfb + (size_t)bh * 16384;  // 32 tiles * 512 frags-of-8
    const bf16x8* KF = (const bf16x8*)kfb + (size_t)bh * 16384;
    const bf16x8* VF = (const bf16x8*)vfb + (size_t)bh * 16384;

    bf16x8 qv[4];
#pragma unroll
    for (int st = 0; st < 4; ++st)
        qv[st] = QF[(size_t)qt * 512 + (qg * 4 + st) * 64 + lane];

    f32x16 o0 = {}, o1 = {};
    float m = -INFINITY, l = 0.f;

    // preload K fragments for first tile of this wave's half
    bf16x8 kc[4], kn[4];
    {
        int t32 = kvh * 32, t64 = t32 >> 1, rh = t32 & 1;
#pragma unroll
        for (int st = 0; st < 4; ++st)
            kc[st] = KF[(size_t)t64 * 512 + (rh * 4 + st) * 64 + lane];
    }

    for (int tt = 0; tt < 32; ++tt) {
        int t32 = kvh * 32 + tt;
        int t64 = t32 >> 1, rh = t32 & 1;

        // QK^T: S^T[k][q], one q-row per lane (Q pre-scaled by 0.125*log2e)
        f32x16 s = {};
#pragma unroll
        for (int st = 0; st < 4; ++st)
            s = __builtin_amdgcn_mfma_f32_32x32x16_bf16(kc[st], qv[st], s, 0, 0, 0);

        // issue V loads (this tile) + K loads (next tile); softmax hides latency
        bf16x8 vv[4];
#pragma unroll
        for (int dr = 0; dr < 2; ++dr)
#pragma unroll
            for (int ksl = 0; ksl < 2; ++ksl)
                vv[dr * 2 + ksl] = VF[(size_t)t64 * 512 + (dr * 4 + rh * 2 + ksl) * 64 + lane];
        {
            int tp = (tt < 31) ? t32 + 1 : t32;
            int p64 = tp >> 1, ph = tp & 1;
#pragma unroll
            for (int st = 0; st < 4; ++st)
                kn[st] = KF[(size_t)p64 * 512 + (ph * 4 + st) * 64 + lane];
        }

        // online softmax (log2 domain): max3 tree, defer-max rescale (THR=8)
        float t0m = max3f(s[0], s[1], s[2]);
        float t1m = max3f(s[3], s[4], s[5]);
        float t2m = max3f(s[6], s[7], s[8]);
        float t3m = max3f(s[9], s[10], s[11]);
        float t4m = max3f(s[12], s[13], s[14]);
        float mx = fmaxf(max3f(t0m, t1m, t2m), max3f(t3m, t4m, s[15]));
        mx = fmaxf(mx, __shfl_xor(mx, 32));
        if (__any(mx - m > 8.0f)) {
            float mn = fmaxf(m, mx);
            float al = __builtin_amdgcn_exp2f(m - mn);
            m = mn;
            l *= al;
#pragma unroll
            for (int i = 0; i < 16; ++i) { o0[i] *= al; o1[i] *= al; }
        }
#pragma unroll
        for (int i = 0; i < 16; ++i) s[i] = __builtin_amdgcn_exp2f(s[i] - m);
        float ts[8];
#pragma unroll
        for (int i = 0; i < 8; ++i) ts[i] = s[i] + s[8 + i];
#pragma unroll
        for (int i = 0; i < 4; ++i) ts[i] = ts[i] + ts[4 + i];
        float sum = (ts[0] + ts[1]) + (ts[2] + ts[3]);
        l += sum;  // own-half partial; cross-half shfl deferred (m symmetric across hi)

        // P^T -> B-fragments: 8 cvt_pk + 4 permlane32_swap (yields both words, no selects)
        bf16x8 pb[2];
#pragma unroll
        for (int ksl = 0; ksl < 2; ++ksl) {
            const int base = ksl * 8;
            unsigned w0 = cvtpk(s[base + 0], s[base + 1]);  // own t-pair  (k=16ksl+4hi+{0,1})
            unsigned w1 = cvtpk(s[base + 2], s[base + 3]);  //             (k=16ksl+4hi+{2,3})
            unsigned w2 = cvtpk(s[base + 4], s[base + 5]);  // own u-pair  (k=16ksl+8+4hi+{0,1})
            unsigned w3 = cvtpk(s[base + 6], s[base + 7]);
            asm("v_permlane32_swap_b32 %0, %1" : "+v"(w0), "+v"(w2));
            asm("v_permlane32_swap_b32 %0, %1" : "+v"(w1), "+v"(w3));
            union { unsigned u[4]; bf16x8 v; } pk;
            pk.u[0] = w0;  // k = 16ksl + 8hi + {0,1}
            pk.u[1] = w1;  //                  {2,3}
            pk.u[2] = w2;  //                  {4,5}
            pk.u[3] = w3;  //                  {6,7}
            pb[ksl] = pk.v;
        }

        // O^T[d][q] += V^T[d][k] @ P^T[k][q]
        o0 = __builtin_amdgcn_mfma_f32_32x32x16_bf16(vv[0], pb[0], o0, 0, 0, 0);
        o0 = __builtin_amdgcn_mfma_f32_32x32x16_bf16(vv[1], pb[1], o0, 0, 0, 0);
        o1 = __builtin_amdgcn_mfma_f32_32x32x16_bf16(vv[2], pb[0], o1, 0, 0, 0);
        o1 = __builtin_amdgcn_mfma_f32_32x32x16_bf16(vv[3], pb[1], o1, 0, 0, 0);

#pragma unroll
        for (int st = 0; st < 4; ++st) kc[st] = kn[st];
    }

    l += __shfl_xor(l, 32);  // deferred cross-half reduce

    // merge the two KV halves through LDS
    __syncthreads();
    if (kvh == 1) {
        Ms[qg][lane] = m; Ls[qg][lane] = l;
#pragma unroll
        for (int i = 0; i < 16; ++i) { Os[qg][i][lane] = o0[i]; Os[qg][16 + i][lane] = o1[i]; }
    }
    __syncthreads();
    if (kvh == 0) {
        float m2 = Ms[qg][lane], l2 = Ls[qg][lane];
        float mn = fmaxf(m, m2);
        float a = __builtin_amdgcn_exp2f(m - mn);
        float b2 = __builtin_amdgcn_exp2f(m2 - mn);
        float linv = 1.f / (l * a + l2 * b2);
        // epilogue: lane holds O^T[d][q=qi]; d = dt*32 + 8*rg + 4*hi + (0..3)
        __hip_bfloat16* crow = ctx + ((size_t)(b * SEQ) + q0 + qi) * MODEL + h * HDIM;
#pragma unroll
        for (int rg = 0; rg < 4; ++rg) {
            float c0[4], c1[4];
#pragma unroll
            for (int e = 0; e < 4; ++e) {
                int i = rg * 4 + e;
                c0[e] = (o0[i] * a + Os[qg][i][lane] * b2) * linv;
                c1[e] = (o1[i] * a + Os[qg][16 + i][lane] * b2) * linv;
            }
            uint2 pk0, pk1;
            pk0.x = cvtpk(c0[0], c0[1]); pk0.y = cvtpk(c0[2], c0[3]);
            pk1.x = cvtpk(c1[0], c1[1]); pk1.y = cvtpk(c1[2], c1[3]);
            *(uint2*)(crow + rg * 8 + hi * 4) = pk0;
            *(uint2*)(crow + 32 + rg * 8 + hi * 4) = pk1;
        }
    }
}

// ---------------- launch ----------------

extern "C" void kernel_launch(void* const* d_in, const int* in_sizes, int n_in,
                              void* d_out, int out_size, void* d_ws, size_t ws_size,
                              hipStream_t stream) {
    const float* emb = (const float*)d_in[0];
    const float* w_qkv = (const float*)d_in[1];
    const float* b_qkv = (const float*)d_in[2];
    const float* w_out = (const float*)d_in[3];
    const float* b_out = (const float*)d_in[4];
    float* out = (float*)d_out;
    char* ws = (char*)d_ws;

    __hip_bfloat16* Xb    = (__hip_bfloat16*)(ws);                       //  8 MB
    __hip_bfloat16* Wqkvt = (__hip_bfloat16*)(ws + ((size_t)8  << 20));  //  6 MB
    __hip_bfloat16* Woutt = (__hip_bfloat16*)(ws + ((size_t)14 << 20));  //  2 MB
    __hip_bfloat16* qbuf  = (__hip_bfloat16*)(ws + ((size_t)16 << 20));  //  8 MB (frag-major)
    __hip_bfloat16* kbuf  = (__hip_bfloat16*)(ws + ((size_t)24 << 20));  //  8 MB (frag-major)
    __hip_bfloat16* vbuf  = (__hip_bfloat16*)(ws + ((size_t)32 << 20));  //  8 MB (frag-major V^T)
    __hip_bfloat16* ctx   = (__hip_bfloat16*)(ws + ((size_t)40 << 20));  //  8 MB

    prep_kernel<<<8192, 256, 0, stream>>>(emb, Xb, w_qkv, Wqkvt, w_out, Woutt);

    gemm_bt_kernel<0><<<dim3(QKVN / 128, NROWS / 128), 256, 0, stream>>>(
        Xb, Wqkvt, b_qkv, nullptr, qbuf, kbuf, vbuf, NROWS, QKVN, MODEL);

    attn_kernel<<<dim3(32, 32), 256, 0, stream>>>(qbuf, kbuf, vbuf, ctx);

    gemm_bt_kernel<1><<<dim3(MODEL / 128, NROWS / 128), 256, 0, stream>>>(
        ctx, Woutt, b_out, out, nullptr, nullptr, nullptr, NROWS, MODEL, MODEL);
}

// Round 11
// 187.583 us; speedup vs baseline: 1.1288x; 1.0589x over previous
//
#include <hip/hip_runtime.h>
#include <hip/hip_bf16.h>

#define MODEL 1024
#define NHEADS 16
#define HDIM 64
#define BATCH 2
#define SEQ 2048
#define NROWS (BATCH*SEQ)   // 4096
#define QKVN (3*MODEL)      // 3072
#define QSCALE 0.1803368801111204f  // 0.125 * log2(e): folded into Q; softmax uses exp2

typedef __bf16 bf16x8 __attribute__((ext_vector_type(8)));
typedef float f32x4 __attribute__((ext_vector_type(4)));
typedef float f32x16 __attribute__((ext_vector_type(16)));

#define GLDS(g, l) __builtin_amdgcn_global_load_lds( \
    (const __attribute__((address_space(1))) void*)(g), \
    (__attribute__((address_space(3))) void*)(l), 16, 0, 0)

__device__ inline unsigned cvtpk(float lo, float hi) {  // lo -> bits[15:0], hi -> bits[31:16]
    unsigned r;
    asm("v_cvt_pk_bf16_f32 %0, %1, %2" : "=v"(r) : "v"(lo), "v"(hi));
    return r;
}

__device__ inline float max3f(float a, float b, float c) {
    float r;
    asm("v_max3_f32 %0, %1, %2, %3" : "=v"(r) : "v"(a), "v"(b), "v"(c));
    return r;
}

// fragment-major index split into additive s- and d-parts (qk: [t64][r2*4+st][lane][8])
__device__ inline int qk_fs(int s) { return ((s >> 6) << 12) + (((s >> 5) & 1) << 11) + ((s & 31) << 3); }
__device__ inline int qk_fd(int d) { return ((d >> 4) << 9) + (((d >> 3) & 1) << 8) + (d & 7); }
// v^T: [t64][dr2*4+ks][lane][8]
__device__ inline int v_fs(int s) { return ((s >> 6) << 12) + (((s >> 4) & 3) << 9) + (((s >> 3) & 1) << 8) + (s & 7); }
__device__ inline int v_fd(int d) { return ((d >> 5) << 11) + ((d & 31) << 3); }

// ---------------- fused prep: emb->bf16, w_qkv^T->bf16, w_out^T->bf16 ----------------
// blocks [0,4096): cvt; [4096,7168): tcvt w_qkv; [7168,8192): tcvt w_out

__global__ __launch_bounds__(256) void prep_kernel(
    const float* __restrict__ emb, __hip_bfloat16* __restrict__ Xb,
    const float* __restrict__ wqkv, __hip_bfloat16* __restrict__ Wqkvt,
    const float* __restrict__ wout, __hip_bfloat16* __restrict__ Woutt)
{
    __shared__ float tile[32][33];
    int bid = blockIdx.x, tid = threadIdx.x;
    if (bid < 4096) {
        int i = (bid * 256 + tid) * 4;
        float4 v = *(const float4*)(emb + i);
        Xb[i + 0] = __float2bfloat16(v.x);
        Xb[i + 1] = __float2bfloat16(v.y);
        Xb[i + 2] = __float2bfloat16(v.z);
        Xb[i + 3] = __float2bfloat16(v.w);
        return;
    }
    const float* in; __hip_bfloat16* out; int K, N, n0, k0;
    if (bid < 7168) {
        int t = bid - 4096; in = wqkv; out = Wqkvt; K = MODEL; N = QKVN;
        n0 = (t % 96) * 32; k0 = (t / 96) * 32;
    } else {
        int t = bid - 7168; in = wout; out = Woutt; K = MODEL; N = MODEL;
        n0 = (t & 31) * 32; k0 = (t >> 5) * 32;
    }
    int tx = tid & 31, ty = tid >> 5;
#pragma unroll
    for (int i = 0; i < 4; ++i)
        tile[ty + i * 8][tx] = in[(size_t)(k0 + ty + i * 8) * N + n0 + tx];
    __syncthreads();
#pragma unroll
    for (int i = 0; i < 4; ++i)
        out[(size_t)(n0 + ty + i * 8) * K + k0 + tx] = __float2bfloat16(tile[tx][ty + i * 8]);
}

// ---------------- GEMM: C[M,N] = A[M,K] @ Bt[N,K]^T + bias (BK=64, st-swizzled LDS) ----------------
// LDS tile [128][64] bf16 XOR-swizzled both sides (rule 21). Natural raster (no XCD swizzle:
// measured +14MB fetch in R10). Per-kk fragment loads + launch_bounds(256,4) -> <=128 regs,
// 4 waves/SIMD. EPI 0: scatter q/k/v to fragment-major buffers; EPI 1: fp32 C + bias.

template<int EPI>
__global__ __launch_bounds__(256, 4) void gemm_bt_kernel(
    const __hip_bfloat16* __restrict__ A, const __hip_bfloat16* __restrict__ Bt,
    const float* __restrict__ bias, float* __restrict__ Cf,
    __hip_bfloat16* __restrict__ qb, __hip_bfloat16* __restrict__ kb,
    __hip_bfloat16* __restrict__ vb, int M, int N, int K)
{
    __shared__ __hip_bfloat16 As[128 * 64];
    __shared__ __hip_bfloat16 Bs[128 * 64];
    int tid = threadIdx.x;
    int lane = tid & 63, wv = tid >> 6;
    int wm = wv >> 1, wn = wv & 1;
    int g = lane >> 4, li = lane & 15;
    int row0 = blockIdx.y * 128, col0 = blockIdx.x * 128;

    // staging source swizzle: lane's slot s'=tid&7, row r=s4*32+(tid>>3); fetch global slot s'^(r&7)
    int cswz = ((tid & 7) ^ ((tid >> 3) & 7)) * 8;

    f32x4 acc[4][4] = {};

    for (int kt = 0; kt < K; kt += 64) {
        __syncthreads();
#pragma unroll
        for (int s4 = 0; s4 < 4; ++s4) {
            int r = s4 * 32 + (tid >> 3);
            GLDS(A + (size_t)(row0 + r) * K + kt + cswz, (char*)As + (size_t)(s4 * 4 + wv) * 1024);
            GLDS(Bt + (size_t)(col0 + r) * K + kt + cswz, (char*)Bs + (size_t)(s4 * 4 + wv) * 1024);
        }
        __syncthreads();
#pragma unroll
        for (int kk = 0; kk < 2; ++kk) {
            bf16x8 a[4], b[4];
#pragma unroll
            for (int m = 0; m < 4; ++m) {
                int row = wm * 64 + m * 16 + li;
                a[m] = *(const bf16x8*)((const char*)As + row * 128 + (((kk * 4 + g) ^ (li & 7)) << 4));
            }
#pragma unroll
            for (int n = 0; n < 4; ++n) {
                int row = wn * 64 + n * 16 + li;
                b[n] = *(const bf16x8*)((const char*)Bs + row * 128 + (((kk * 4 + g) ^ (li & 7)) << 4));
            }
#pragma unroll
            for (int m = 0; m < 4; ++m)
#pragma unroll
                for (int n = 0; n < 4; ++n)
                    acc[m][n] = __builtin_amdgcn_mfma_f32_16x16x32_bf16(a[m], b[n], acc[m][n], 0, 0, 0);
        }
    }

    if (EPI == 1) {
#pragma unroll
        for (int m = 0; m < 4; ++m) {
            int row = row0 + wm * 64 + m * 16 + g * 4;
#pragma unroll
            for (int n = 0; n < 4; ++n) {
                int col = col0 + wn * 64 + n * 16 + li;
                float bv = bias[col];
#pragma unroll
                for (int r = 0; r < 4; ++r)
                    Cf[(size_t)(row + r) * N + col] = acc[m][n][r] + bv;
            }
        }
    } else {
        // hoisted per-n scatter info
        __hip_bfloat16* dstn[4];
        float bvn[4], qmn[4];
        int tpn[4];
#pragma unroll
        for (int n = 0; n < 4; ++n) {
            int col = col0 + wn * 64 + n * 16 + li;
            int h = col / 192;
            int rem = col - h * 192;
            int t = rem >> 6, d = rem & 63;
            tpn[n] = t;
            qmn[n] = (t == 0) ? QSCALE : 1.0f;
            bvn[n] = bias[col];
            __hip_bfloat16* base = (t == 0) ? qb : ((t == 1) ? kb : vb);
            dstn[n] = base + (size_t)h * (SEQ * HDIM) + ((t == 2) ? v_fd(d) : qk_fd(d));
        }
#pragma unroll
        for (int m = 0; m < 4; ++m)
#pragma unroll
            for (int r = 0; r < 4; ++r) {
                int row = row0 + wm * 64 + m * 16 + g * 4 + r;
                int s = row & 2047;
                int bofs = (row >> 11) * (NHEADS * SEQ * HDIM);
                int fsqk = qk_fs(s), fsv = v_fs(s);
#pragma unroll
                for (int n = 0; n < 4; ++n) {
                    float val = (acc[m][n][r] + bvn[n]) * qmn[n];
                    int off = bofs + ((tpn[n] == 2) ? fsv : fsqk);
                    dstn[n][off] = __float2bfloat16(val);
                }
            }
    }
}

// ---------------- flash attention (swapped-QK^T, split-KV, KVBLK=32) — R10-proven, unchanged ----------------

__global__ __launch_bounds__(256, 4) void attn_kernel(
    const __hip_bfloat16* __restrict__ qfb, const __hip_bfloat16* __restrict__ kfb,
    const __hip_bfloat16* __restrict__ vfb, __hip_bfloat16* __restrict__ ctx)
{
    __shared__ float Ms[2][64], Ls[2][64], Os[2][32][64];
    int tid = threadIdx.x;
    int lane = tid & 63, w = tid >> 6;
    int qg = w & 1, kvh = w >> 1;
    int qi = lane & 31, hi = lane >> 5;

    // XCD-chunked swizzle: bid%8 -> XCD; chunk of 128 consecutive swz = 4 heads
    int bid = blockIdx.y * 32 + blockIdx.x;
    int swz = (bid & 7) * 128 + (bid >> 3);
    int bh = swz >> 5, qt = swz & 31;
    int b = bh >> 4, h = bh & 15;
    int q0 = qt * 64 + qg * 32;

    const bf16x8* QF = (const bf16x8*)qfb + (size_t)bh * 16384;  // 32 tiles * 512 frags-of-8
    const bf16x8* KF = (const bf16x8*)kfb + (size_t)bh * 16384;
    const bf16x8* VF = (const bf16x8*)vfb + (size_t)bh * 16384;

    bf16x8 qv[4];
#pragma unroll
    for (int st = 0; st < 4; ++st)
        qv[st] = QF[(size_t)qt * 512 + (qg * 4 + st) * 64 + lane];

    f32x16 o0 = {}, o1 = {};
    float m = -INFINITY, l = 0.f;

    // preload K fragments for first tile of this wave's half
    bf16x8 kc[4], kn[4];
    {
        int t32 = kvh * 32, t64 = t32 >> 1, rh = t32 & 1;
#pragma unroll
        for (int st = 0; st < 4; ++st)
            kc[st] = KF[(size_t)t64 * 512 + (rh * 4 + st) * 64 + lane];
    }

    for (int tt = 0; tt < 32; ++tt) {
        int t32 = kvh * 32 + tt;
        int t64 = t32 >> 1, rh = t32 & 1;

        // QK^T: S^T[k][q], one q-row per lane (Q pre-scaled by 0.125*log2e)
        f32x16 s = {};
#pragma unroll
        for (int st = 0; st < 4; ++st)
            s = __builtin_amdgcn_mfma_f32_32x32x16_bf16(kc[st], qv[st], s, 0, 0, 0);

        // issue V loads (this tile) + K loads (next tile); softmax hides latency
        bf16x8 vv[4];
#pragma unroll
        for (int dr = 0; dr < 2; ++dr)
#pragma unroll
            for (int ksl = 0; ksl < 2; ++ksl)
                vv[dr * 2 + ksl] = VF[(size_t)t64 * 512 + (dr * 4 + rh * 2 + ksl) * 64 + lane];
        {
            int tp = (tt < 31) ? t32 + 1 : t32;
            int p64 = tp >> 1, ph = tp & 1;
#pragma unroll
            for (int st = 0; st < 4; ++st)
                kn[st] = KF[(size_t)p64 * 512 + (ph * 4 + st) * 64 + lane];
        }

        // online softmax (log2 domain): max3 tree, defer-max rescale (THR=8)
        float t0m = max3f(s[0], s[1], s[2]);
        float t1m = max3f(s[3], s[4], s[5]);
        float t2m = max3f(s[6], s[7], s[8]);
        float t3m = max3f(s[9], s[10], s[11]);
        float t4m = max3f(s[12], s[13], s[14]);
        float mx = fmaxf(max3f(t0m, t1m, t2m), max3f(t3m, t4m, s[15]));
        mx = fmaxf(mx, __shfl_xor(mx, 32));
        if (__any(mx - m > 8.0f)) {
            float mn = fmaxf(m, mx);
            float al = __builtin_amdgcn_exp2f(m - mn);
            m = mn;
            l *= al;
#pragma unroll
            for (int i = 0; i < 16; ++i) { o0[i] *= al; o1[i] *= al; }
        }
#pragma unroll
        for (int i = 0; i < 16; ++i) s[i] = __builtin_amdgcn_exp2f(s[i] - m);
        float ts[8];
#pragma unroll
        for (int i = 0; i < 8; ++i) ts[i] = s[i] + s[8 + i];
#pragma unroll
        for (int i = 0; i < 4; ++i) ts[i] = ts[i] + ts[4 + i];
        float sum = (ts[0] + ts[1]) + (ts[2] + ts[3]);
        l += sum;  // own-half partial; cross-half shfl deferred (m symmetric across hi)

        // P^T -> B-fragments: 8 cvt_pk + 4 permlane32_swap (yields both words, no selects)
        bf16x8 pb[2];
#pragma unroll
        for (int ksl = 0; ksl < 2; ++ksl) {
            const int base = ksl * 8;
            unsigned w0 = cvtpk(s[base + 0], s[base + 1]);  // own t-pair  (k=16ksl+4hi+{0,1})
            unsigned w1 = cvtpk(s[base + 2], s[base + 3]);  //             (k=16ksl+4hi+{2,3})
            unsigned w2 = cvtpk(s[base + 4], s[base + 5]);  // own u-pair  (k=16ksl+8+4hi+{0,1})
            unsigned w3 = cvtpk(s[base + 6], s[base + 7]);
            asm("v_permlane32_swap_b32 %0, %1" : "+v"(w0), "+v"(w2));
            asm("v_permlane32_swap_b32 %0, %1" : "+v"(w1), "+v"(w3));
            union { unsigned u[4]; bf16x8 v; } pk;
            pk.u[0] = w0;  // k = 16ksl + 8hi + {0,1}
            pk.u[1] = w1;  //                  {2,3}
            pk.u[2] = w2;  //                  {4,5}
            pk.u[3] = w3;  //                  {6,7}
            pb[ksl] = pk.v;
        }

        // O^T[d][q] += V^T[d][k] @ P^T[k][q]
        o0 = __builtin_amdgcn_mfma_f32_32x32x16_bf16(vv[0], pb[0], o0, 0, 0, 0);
        o0 = __builtin_amdgcn_mfma_f32_32x32x16_bf16(vv[1], pb[1], o0, 0, 0, 0);
        o1 = __builtin_amdgcn_mfma_f32_32x32x16_bf16(vv[2], pb[0], o1, 0, 0, 0);
        o1 = __builtin_amdgcn_mfma_f32_32x32x16_bf16(vv[3], pb[1], o1, 0, 0, 0);

#pragma unroll
        for (int st = 0; st < 4; ++st) kc[st] = kn[st];
    }

    l += __shfl_xor(l, 32);  // deferred cross-half reduce

    // merge the two KV halves through LDS
    __syncthreads();
    if (kvh == 1) {
        Ms[qg][lane] = m; Ls[qg][lane] = l;
#pragma unroll
        for (int i = 0; i < 16; ++i) { Os[qg][i][lane] = o0[i]; Os[qg][16 + i][lane] = o1[i]; }
    }
    __syncthreads();
    if (kvh == 0) {
        float m2 = Ms[qg][lane], l2 = Ls[qg][lane];
        float mn = fmaxf(m, m2);
        float a = __builtin_amdgcn_exp2f(m - mn);
        float b2 = __builtin_amdgcn_exp2f(m2 - mn);
        float linv = 1.f / (l * a + l2 * b2);
        // epilogue: lane holds O^T[d][q=qi]; d = dt*32 + 8*rg + 4*hi + (0..3)
        __hip_bfloat16* crow = ctx + ((size_t)(b * SEQ) + q0 + qi) * MODEL + h * HDIM;
#pragma unroll
        for (int rg = 0; rg < 4; ++rg) {
            float c0[4], c1[4];
#pragma unroll
            for (int e = 0; e < 4; ++e) {
                int i = rg * 4 + e;
                c0[e] = (o0[i] * a + Os[qg][i][lane] * b2) * linv;
                c1[e] = (o1[i] * a + Os[qg][16 + i][lane] * b2) * linv;
            }
            uint2 pk0, pk1;
            pk0.x = cvtpk(c0[0], c0[1]); pk0.y = cvtpk(c0[2], c0[3]);
            pk1.x = cvtpk(c1[0], c1[1]); pk1.y = cvtpk(c1[2], c1[3]);
            *(uint2*)(crow + rg * 8 + hi * 4) = pk0;
            *(uint2*)(crow + 32 + rg * 8 + hi * 4) = pk1;
        }
    }
}

// ---------------- launch ----------------

extern "C" void kernel_launch(void* const* d_in, const int* in_sizes, int n_in,
                              void* d_out, int out_size, void* d_ws, size_t ws_size,
                              hipStream_t stream) {
    const float* emb = (const float*)d_in[0];
    const float* w_qkv = (const float*)d_in[1];
    const float* b_qkv = (const float*)d_in[2];
    const float* w_out = (const float*)d_in[3];
    const float* b_out = (const float*)d_in[4];
    float* out = (float*)d_out;
    char* ws = (char*)d_ws;

    __hip_bfloat16* Xb    = (__hip_bfloat16*)(ws);                       //  8 MB
    __hip_bfloat16* Wqkvt = (__hip_bfloat16*)(ws + ((size_t)8  << 20));  //  6 MB
    __hip_bfloat16* Woutt = (__hip_bfloat16*)(ws + ((size_t)14 << 20));  //  2 MB
    __hip_bfloat16* qbuf  = (__hip_bfloat16*)(ws + ((size_t)16 << 20));  //  8 MB (frag-major)
    __hip_bfloat16* kbuf  = (__hip_bfloat16*)(ws + ((size_t)24 << 20));  //  8 MB (frag-major)
    __hip_bfloat16* vbuf  = (__hip_bfloat16*)(ws + ((size_t)32 << 20));  //  8 MB (frag-major V^T)
    __hip_bfloat16* ctx   = (__hip_bfloat16*)(ws + ((size_t)40 << 20));  //  8 MB

    prep_kernel<<<8192, 256, 0, stream>>>(emb, Xb, w_qkv, Wqkvt, w_out, Woutt);

    gemm_bt_kernel<0><<<dim3(QKVN / 128, NROWS / 128), 256, 0, stream>>>(
        Xb, Wqkvt, b_qkv, nullptr, qbuf, kbuf, vbuf, NROWS, QKVN, MODEL);

    attn_kernel<<<dim3(32, 32), 256, 0, stream>>>(qbuf, kbuf, vbuf, ctx);

    gemm_bt_kernel<1><<<dim3(MODEL / 128, NROWS / 128), 256, 0, stream>>>(
        ctx, Woutt, b_out, out, nullptr, nullptr, nullptr, NROWS, MODEL, MODEL);
}

// Round 12
// 183.242 us; speedup vs baseline: 1.1555x; 1.0237x over previous
//
#include <hip/hip_runtime.h>
#include <hip/hip_bf16.h>

#define MODEL 1024
#define NHEADS 16
#define HDIM 64
#define BATCH 2
#define SEQ 2048
#define NROWS (BATCH*SEQ)   // 4096
#define QKVN (3*MODEL)      // 3072
#define QSCALE 0.1803368801111204f  // 0.125 * log2(e): folded into Q; softmax uses exp2

typedef __bf16 bf16x8 __attribute__((ext_vector_type(8)));
typedef float f32x4 __attribute__((ext_vector_type(4)));
typedef float f32x16 __attribute__((ext_vector_type(16)));

#define GLDS(g, l) __builtin_amdgcn_global_load_lds( \
    (const __attribute__((address_space(1))) void*)(g), \
    (__attribute__((address_space(3))) void*)(l), 16, 0, 0)

__device__ inline unsigned cvtpk(float lo, float hi) {  // lo -> bits[15:0], hi -> bits[31:16]
    unsigned r;
    asm("v_cvt_pk_bf16_f32 %0, %1, %2" : "=v"(r) : "v"(lo), "v"(hi));
    return r;
}

__device__ inline float max3f(float a, float b, float c) {
    float r;
    asm("v_max3_f32 %0, %1, %2, %3" : "=v"(r) : "v"(a), "v"(b), "v"(c));
    return r;
}

// fragment-major index split into additive s- and d-parts (qk: [t64][r2*4+st][lane][8])
__device__ inline int qk_fs(int s) { return ((s >> 6) << 12) + (((s >> 5) & 1) << 11) + ((s & 31) << 3); }
__device__ inline int qk_fd(int d) { return ((d >> 4) << 9) + (((d >> 3) & 1) << 8) + (d & 7); }
// v^T: [t64][dr2*4+ks][lane][8]
__device__ inline int v_fs(int s) { return ((s >> 6) << 12) + (((s >> 4) & 3) << 9) + (((s >> 3) & 1) << 8) + (s & 7); }
__device__ inline int v_fd(int d) { return ((d >> 5) << 11) + ((d & 31) << 3); }

// ---------------- fused prep: emb->bf16, w_qkv^T->bf16, w_out^T->bf16 ----------------
// blocks [0,4096): cvt; [4096,7168): tcvt w_qkv; [7168,8192): tcvt w_out

__global__ __launch_bounds__(256) void prep_kernel(
    const float* __restrict__ emb, __hip_bfloat16* __restrict__ Xb,
    const float* __restrict__ wqkv, __hip_bfloat16* __restrict__ Wqkvt,
    const float* __restrict__ wout, __hip_bfloat16* __restrict__ Woutt)
{
    __shared__ float tile[32][33];
    int bid = blockIdx.x, tid = threadIdx.x;
    if (bid < 4096) {
        int i = (bid * 256 + tid) * 4;
        float4 v = *(const float4*)(emb + i);
        Xb[i + 0] = __float2bfloat16(v.x);
        Xb[i + 1] = __float2bfloat16(v.y);
        Xb[i + 2] = __float2bfloat16(v.z);
        Xb[i + 3] = __float2bfloat16(v.w);
        return;
    }
    const float* in; __hip_bfloat16* out; int K, N, n0, k0;
    if (bid < 7168) {
        int t = bid - 4096; in = wqkv; out = Wqkvt; K = MODEL; N = QKVN;
        n0 = (t % 96) * 32; k0 = (t / 96) * 32;
    } else {
        int t = bid - 7168; in = wout; out = Woutt; K = MODEL; N = MODEL;
        n0 = (t & 31) * 32; k0 = (t >> 5) * 32;
    }
    int tx = tid & 31, ty = tid >> 5;
#pragma unroll
    for (int i = 0; i < 4; ++i)
        tile[ty + i * 8][tx] = in[(size_t)(k0 + ty + i * 8) * N + n0 + tx];
    __syncthreads();
#pragma unroll
    for (int i = 0; i < 4; ++i)
        out[(size_t)(n0 + ty + i * 8) * K + k0 + tx] = __float2bfloat16(tile[tx][ty + i * 8]);
}

// ---------------- GEMM: C[M,N] = A[M,K] @ Bt[N,K]^T + bias (BK=64, st-swizzled LDS) ----------------
// BM=128 fixed; BN template (128 for gemm0, 64 for gemm1 -> 512 blocks = 2/CU occupancy).
// LDS XOR-swizzled both sides (rule 21). Natural raster. Per-kk fragment loads, <=128 regs.
// EPI 0: scatter q/k/v to fragment-major buffers; EPI 1: fp32 C + bias.

template<int EPI, int BN>
__global__ __launch_bounds__(256, 4) void gemm_bt_kernel(
    const __hip_bfloat16* __restrict__ A, const __hip_bfloat16* __restrict__ Bt,
    const float* __restrict__ bias, float* __restrict__ Cf,
    __hip_bfloat16* __restrict__ qb, __hip_bfloat16* __restrict__ kb,
    __hip_bfloat16* __restrict__ vb, int M, int N, int K)
{
    constexpr int NF = BN / 32;       // n-frags per wave
    constexpr int BR = BN / 32;       // B staging rounds
    __shared__ __hip_bfloat16 As[128 * 64];
    __shared__ __hip_bfloat16 Bs[BN * 64];
    int tid = threadIdx.x;
    int lane = tid & 63, wv = tid >> 6;
    int wm = wv >> 1, wn = wv & 1;
    int g = lane >> 4, li = lane & 15;
    int row0 = blockIdx.y * 128, col0 = blockIdx.x * BN;

    // staging source swizzle: lane's slot s'=tid&7, row r=s4*32+(tid>>3); fetch global slot s'^(r&7)
    int cswz = ((tid & 7) ^ ((tid >> 3) & 7)) * 8;

    f32x4 acc[4][NF] = {};

    for (int kt = 0; kt < K; kt += 64) {
        __syncthreads();
#pragma unroll
        for (int s4 = 0; s4 < 4; ++s4) {
            int r = s4 * 32 + (tid >> 3);
            GLDS(A + (size_t)(row0 + r) * K + kt + cswz, (char*)As + (size_t)(s4 * 4 + wv) * 1024);
        }
#pragma unroll
        for (int s4 = 0; s4 < BR; ++s4) {
            int r = s4 * 32 + (tid >> 3);
            GLDS(Bt + (size_t)(col0 + r) * K + kt + cswz, (char*)Bs + (size_t)(s4 * 4 + wv) * 1024);
        }
        __syncthreads();
#pragma unroll
        for (int kk = 0; kk < 2; ++kk) {
            bf16x8 a[4], b[NF];
#pragma unroll
            for (int m = 0; m < 4; ++m) {
                int row = wm * 64 + m * 16 + li;
                a[m] = *(const bf16x8*)((const char*)As + row * 128 + (((kk * 4 + g) ^ (li & 7)) << 4));
            }
#pragma unroll
            for (int n = 0; n < NF; ++n) {
                int row = wn * (BN / 2) + n * 16 + li;
                b[n] = *(const bf16x8*)((const char*)Bs + row * 128 + (((kk * 4 + g) ^ (li & 7)) << 4));
            }
#pragma unroll
            for (int m = 0; m < 4; ++m)
#pragma unroll
                for (int n = 0; n < NF; ++n)
                    acc[m][n] = __builtin_amdgcn_mfma_f32_16x16x32_bf16(a[m], b[n], acc[m][n], 0, 0, 0);
        }
    }

    if (EPI == 1) {
#pragma unroll
        for (int m = 0; m < 4; ++m) {
            int row = row0 + wm * 64 + m * 16 + g * 4;
#pragma unroll
            for (int n = 0; n < NF; ++n) {
                int col = col0 + wn * (BN / 2) + n * 16 + li;
                float bv = bias[col];
#pragma unroll
                for (int r = 0; r < 4; ++r)
                    Cf[(size_t)(row + r) * N + col] = acc[m][n][r] + bv;
            }
        }
    } else {
        // hoisted per-n scatter info
        __hip_bfloat16* dstn[NF];
        float bvn[NF], qmn[NF];
        int tpn[NF];
#pragma unroll
        for (int n = 0; n < NF; ++n) {
            int col = col0 + wn * (BN / 2) + n * 16 + li;
            int h = col / 192;
            int rem = col - h * 192;
            int t = rem >> 6, d = rem & 63;
            tpn[n] = t;
            qmn[n] = (t == 0) ? QSCALE : 1.0f;
            bvn[n] = bias[col];
            __hip_bfloat16* base = (t == 0) ? qb : ((t == 1) ? kb : vb);
            dstn[n] = base + (size_t)h * (SEQ * HDIM) + ((t == 2) ? v_fd(d) : qk_fd(d));
        }
#pragma unroll
        for (int m = 0; m < 4; ++m)
#pragma unroll
            for (int r = 0; r < 4; ++r) {
                int row = row0 + wm * 64 + m * 16 + g * 4 + r;
                int s = row & 2047;
                int bofs = (row >> 11) * (NHEADS * SEQ * HDIM);
                int fsqk = qk_fs(s), fsv = v_fs(s);
#pragma unroll
                for (int n = 0; n < NF; ++n) {
                    float val = (acc[m][n][r] + bvn[n]) * qmn[n];
                    int off = bofs + ((tpn[n] == 2) ? fsv : fsqk);
                    dstn[n][off] = __float2bfloat16(val);
                }
            }
    }
}

// ---------------- flash attention (swapped-QK^T, split-KV, KVBLK=32) + setprio on MFMA ----------------

__global__ __launch_bounds__(256, 4) void attn_kernel(
    const __hip_bfloat16* __restrict__ qfb, const __hip_bfloat16* __restrict__ kfb,
    const __hip_bfloat16* __restrict__ vfb, __hip_bfloat16* __restrict__ ctx)
{
    __shared__ float Ms[2][64], Ls[2][64], Os[2][32][64];
    int tid = threadIdx.x;
    int lane = tid & 63, w = tid >> 6;
    int qg = w & 1, kvh = w >> 1;
    int qi = lane & 31, hi = lane >> 5;

    // XCD-chunked swizzle: bid%8 -> XCD; chunk of 128 consecutive swz = 4 heads
    int bid = blockIdx.y * 32 + blockIdx.x;
    int swz = (bid & 7) * 128 + (bid >> 3);
    int bh = swz >> 5, qt = swz & 31;
    int b = bh >> 4, h = bh & 15;
    int q0 = qt * 64 + qg * 32;

    const bf16x8* QF = (const bf16x8*)qfb + (size_t)bh * 16384;  // 32 tiles * 512 frags-of-8
    const bf16x8* KF = (const bf16x8*)kfb + (size_t)bh * 16384;
    const bf16x8* VF = (const bf16x8*)vfb + (size_t)bh * 16384;

    bf16x8 qv[4];
#pragma unroll
    for (int st = 0; st < 4; ++st)
        qv[st] = QF[(size_t)qt * 512 + (qg * 4 + st) * 64 + lane];

    f32x16 o0 = {}, o1 = {};
    float m = -INFINITY, l = 0.f;

    // preload K fragments for first tile of this wave's half
    bf16x8 kc[4], kn[4];
    {
        int t32 = kvh * 32, t64 = t32 >> 1, rh = t32 & 1;
#pragma unroll
        for (int st = 0; st < 4; ++st)
            kc[st] = KF[(size_t)t64 * 512 + (rh * 4 + st) * 64 + lane];
    }

    for (int tt = 0; tt < 32; ++tt) {
        int t32 = kvh * 32 + tt;
        int t64 = t32 >> 1, rh = t32 & 1;

        // QK^T: S^T[k][q], one q-row per lane (Q pre-scaled by 0.125*log2e)
        f32x16 s = {};
        __builtin_amdgcn_s_setprio(1);
#pragma unroll
        for (int st = 0; st < 4; ++st)
            s = __builtin_amdgcn_mfma_f32_32x32x16_bf16(kc[st], qv[st], s, 0, 0, 0);
        __builtin_amdgcn_s_setprio(0);

        // issue V loads (this tile) + K loads (next tile); softmax hides latency
        bf16x8 vv[4];
#pragma unroll
        for (int dr = 0; dr < 2; ++dr)
#pragma unroll
            for (int ksl = 0; ksl < 2; ++ksl)
                vv[dr * 2 + ksl] = VF[(size_t)t64 * 512 + (dr * 4 + rh * 2 + ksl) * 64 + lane];
        {
            int tp = (tt < 31) ? t32 + 1 : t32;
            int p64 = tp >> 1, ph = tp & 1;
#pragma unroll
            for (int st = 0; st < 4; ++st)
                kn[st] = KF[(size_t)p64 * 512 + (ph * 4 + st) * 64 + lane];
        }

        // online softmax (log2 domain): max3 tree, defer-max rescale (THR=8)
        float t0m = max3f(s[0], s[1], s[2]);
        float t1m = max3f(s[3], s[4], s[5]);
        float t2m = max3f(s[6], s[7], s[8]);
        float t3m = max3f(s[9], s[10], s[11]);
        float t4m = max3f(s[12], s[13], s[14]);
        float mx = fmaxf(max3f(t0m, t1m, t2m), max3f(t3m, t4m, s[15]));
        mx = fmaxf(mx, __shfl_xor(mx, 32));
        if (__any(mx - m > 8.0f)) {
            float mn = fmaxf(m, mx);
            float al = __builtin_amdgcn_exp2f(m - mn);
            m = mn;
            l *= al;
#pragma unroll
            for (int i = 0; i < 16; ++i) { o0[i] *= al; o1[i] *= al; }
        }
#pragma unroll
        for (int i = 0; i < 16; ++i) s[i] = __builtin_amdgcn_exp2f(s[i] - m);
        float ts[8];
#pragma unroll
        for (int i = 0; i < 8; ++i) ts[i] = s[i] + s[8 + i];
#pragma unroll
        for (int i = 0; i < 4; ++i) ts[i] = ts[i] + ts[4 + i];
        float sum = (ts[0] + ts[1]) + (ts[2] + ts[3]);
        l += sum;  // own-half partial; cross-half shfl deferred (m symmetric across hi)

        // P^T -> B-fragments: 8 cvt_pk + 4 permlane32_swap (yields both words, no selects)
        bf16x8 pb[2];
#pragma unroll
        for (int ksl = 0; ksl < 2; ++ksl) {
            const int base = ksl * 8;
            unsigned w0 = cvtpk(s[base + 0], s[base + 1]);  // own t-pair  (k=16ksl+4hi+{0,1})
            unsigned w1 = cvtpk(s[base + 2], s[base + 3]);  //             (k=16ksl+4hi+{2,3})
            unsigned w2 = cvtpk(s[base + 4], s[base + 5]);  // own u-pair  (k=16ksl+8+4hi+{0,1})
            unsigned w3 = cvtpk(s[base + 6], s[base + 7]);
            asm("v_permlane32_swap_b32 %0, %1" : "+v"(w0), "+v"(w2));
            asm("v_permlane32_swap_b32 %0, %1" : "+v"(w1), "+v"(w3));
            union { unsigned u[4]; bf16x8 v; } pk;
            pk.u[0] = w0;  // k = 16ksl + 8hi + {0,1}
            pk.u[1] = w1;  //                  {2,3}
            pk.u[2] = w2;  //                  {4,5}
            pk.u[3] = w3;  //                  {6,7}
            pb[ksl] = pk.v;
        }

        // O^T[d][q] += V^T[d][k] @ P^T[k][q]
        __builtin_amdgcn_s_setprio(1);
        o0 = __builtin_amdgcn_mfma_f32_32x32x16_bf16(vv[0], pb[0], o0, 0, 0, 0);
        o0 = __builtin_amdgcn_mfma_f32_32x32x16_bf16(vv[1], pb[1], o0, 0, 0, 0);
        o1 = __builtin_amdgcn_mfma_f32_32x32x16_bf16(vv[2], pb[0], o1, 0, 0, 0);
        o1 = __builtin_amdgcn_mfma_f32_32x32x16_bf16(vv[3], pb[1], o1, 0, 0, 0);
        __builtin_amdgcn_s_setprio(0);

#pragma unroll
        for (int st = 0; st < 4; ++st) kc[st] = kn[st];
    }

    l += __shfl_xor(l, 32);  // deferred cross-half reduce

    // merge the two KV halves through LDS
    __syncthreads();
    if (kvh == 1) {
        Ms[qg][lane] = m; Ls[qg][lane] = l;
#pragma unroll
        for (int i = 0; i < 16; ++i) { Os[qg][i][lane] = o0[i]; Os[qg][16 + i][lane] = o1[i]; }
    }
    __syncthreads();
    if (kvh == 0) {
        float m2 = Ms[qg][lane], l2 = Ls[qg][lane];
        float mn = fmaxf(m, m2);
        float a = __builtin_amdgcn_exp2f(m - mn);
        float b2 = __builtin_amdgcn_exp2f(m2 - mn);
        float linv = 1.f / (l * a + l2 * b2);
        // epilogue: lane holds O^T[d][q=qi]; d = dt*32 + 8*rg + 4*hi + (0..3)
        __hip_bfloat16* crow = ctx + ((size_t)(b * SEQ) + q0 + qi) * MODEL + h * HDIM;
#pragma unroll
        for (int rg = 0; rg < 4; ++rg) {
            float c0[4], c1[4];
#pragma unroll
            for (int e = 0; e < 4; ++e) {
                int i = rg * 4 + e;
                c0[e] = (o0[i] * a + Os[qg][i][lane] * b2) * linv;
                c1[e] = (o1[i] * a + Os[qg][16 + i][lane] * b2) * linv;
            }
            uint2 pk0, pk1;
            pk0.x = cvtpk(c0[0], c0[1]); pk0.y = cvtpk(c0[2], c0[3]);
            pk1.x = cvtpk(c1[0], c1[1]); pk1.y = cvtpk(c1[2], c1[3]);
            *(uint2*)(crow + rg * 8 + hi * 4) = pk0;
            *(uint2*)(crow + 32 + rg * 8 + hi * 4) = pk1;
        }
    }
}

// ---------------- launch ----------------

extern "C" void kernel_launch(void* const* d_in, const int* in_sizes, int n_in,
                              void* d_out, int out_size, void* d_ws, size_t ws_size,
                              hipStream_t stream) {
    const float* emb = (const float*)d_in[0];
    const float* w_qkv = (const float*)d_in[1];
    const float* b_qkv = (const float*)d_in[2];
    const float* w_out = (const float*)d_in[3];
    const float* b_out = (const float*)d_in[4];
    float* out = (float*)d_out;
    char* ws = (char*)d_ws;

    __hip_bfloat16* Xb    = (__hip_bfloat16*)(ws);                       //  8 MB
    __hip_bfloat16* Wqkvt = (__hip_bfloat16*)(ws + ((size_t)8  << 20));  //  6 MB
    __hip_bfloat16* Woutt = (__hip_bfloat16*)(ws + ((size_t)14 << 20));  //  2 MB
    __hip_bfloat16* qbuf  = (__hip_bfloat16*)(ws + ((size_t)16 << 20));  //  8 MB (frag-major)
    __hip_bfloat16* kbuf  = (__hip_bfloat16*)(ws + ((size_t)24 << 20));  //  8 MB (frag-major)
    __hip_bfloat16* vbuf  = (__hip_bfloat16*)(ws + ((size_t)32 << 20));  //  8 MB (frag-major V^T)
    __hip_bfloat16* ctx   = (__hip_bfloat16*)(ws + ((size_t)40 << 20));  //  8 MB

    prep_kernel<<<8192, 256, 0, stream>>>(emb, Xb, w_qkv, Wqkvt, w_out, Woutt);

    gemm_bt_kernel<0, 128><<<dim3(QKVN / 128, NROWS / 128), 256, 0, stream>>>(
        Xb, Wqkvt, b_qkv, nullptr, qbuf, kbuf, vbuf, NROWS, QKVN, MODEL);

    attn_kernel<<<dim3(32, 32), 256, 0, stream>>>(qbuf, kbuf, vbuf, ctx);

    gemm_bt_kernel<1, 64><<<dim3(MODEL / 64, NROWS / 128), 256, 0, stream>>>(
        ctx, Woutt, b_out, out, nullptr, nullptr, nullptr, NROWS, MODEL, MODEL);
}